// Round 6
// baseline (503.385 us; speedup 1.0000x reference)
//
#include <hip/hip_runtime.h>
#include <stdint.h>

#define N_NODES 4096
#define NNN ((int64_t)N_NODES * (int64_t)N_NODES)
#define TOTAL4 (NNN / 4)
#define NC 12
// floor(0.9 * (N*N - 1)) = 15099493 (frac = 0.5)
#define K0_RANK 15099493u

// META layout (u32 words)
#define M_HIST1 0
#define M_HISTA 4096
#define M_HISTB 8192
#define M_DEG   8448
#define M_CNT   12544
#define M_MXB   12545
#define M_MXS   12546
#define M_SEL   12552
#define M_WORDS 13312

typedef __attribute__((ext_vector_type(8))) short short8v;
typedef __attribute__((ext_vector_type(4))) short short4v;
typedef __attribute__((ext_vector_type(4))) float f32x4;

static __device__ __forceinline__ uint32_t f2key(float f) {
    uint32_t x = __float_as_uint(f);
    return (x & 0x80000000u) ? ~x : (x | 0x80000000u);
}
static __device__ __forceinline__ float key2f(uint32_t k) {
    uint32_t x = (k & 0x80000000u) ? (k & 0x7FFFFFFFu) : ~k;
    return __uint_as_float(x);
}
// RNE float->bf16 bits (finite values only)
static __device__ __forceinline__ ushort f2bf(float f) {
    uint32_t u = __float_as_uint(f);
    return (ushort)((u + 0x7FFFu + ((u >> 16) & 1u)) >> 16);
}
static __device__ __forceinline__ float bf2f(ushort b) {
    return __uint_as_float(((uint32_t)b) << 16);
}

static __device__ __forceinline__ void select_bin(const uint32_t* __restrict__ gh,
        int nb, uint32_t target, uint32_t* hl, uint32_t* sc, uint32_t* out) {
    int t = threadIdx.x;
    int per = nb >> 8;
    for (int i = t; i < nb; i += 256) hl[i] = gh[i];
    __syncthreads();
    uint32_t p = 0;
    for (int i = 0; i < per; ++i) p += hl[t * per + i];
    sc[t] = p;
    __syncthreads();
    for (int d = 1; d < 256; d <<= 1) {
        uint32_t v = (t >= d) ? sc[t - d] : 0u;
        __syncthreads();
        sc[t] += v;
        __syncthreads();
    }
    uint32_t excl = sc[t] - p;
    if (p > 0 && target >= excl && target < excl + p) {
        uint32_t cum = excl; int b = t * per;
        while (cum + hl[b] <= target) { cum += hl[b]; ++b; }
        out[0] = (uint32_t)b; out[1] = target - cum;
    }
    __syncthreads();
}

// ---------------------------------------------------------------------------
// 1) agg = sum_c w[c]*attn[c] + b ; per-block hist slice; zero META
// ---------------------------------------------------------------------------
__global__ __launch_bounds__(256) void agg_kernel(const float* __restrict__ attn,
        const float* __restrict__ w, const float* __restrict__ bb,
        float* __restrict__ agg, uint32_t* __restrict__ slice,
        uint32_t* __restrict__ meta) {
    if (blockIdx.x < 52) meta[blockIdx.x * 256 + threadIdx.x] = 0;
    __shared__ uint32_t h[4096];
    for (int i = threadIdx.x; i < 4096; i += 256) h[i] = 0;
    float wr[NC];
#pragma unroll
    for (int c = 0; c < NC; ++c) wr[c] = w[c];
    float b0 = bb[0];
    __syncthreads();
    const float4* a4 = (const float4*)attn;
    float4* o4 = (float4*)agg;
    for (int64_t i = (int64_t)blockIdx.x * 256 + threadIdx.x; i < TOTAL4; i += (int64_t)1024 * 256) {
        float ax = b0, ay = b0, az = b0, aw = b0;
#pragma unroll
        for (int c = 0; c < NC; ++c) {
            float4 t = a4[(int64_t)c * TOTAL4 + i];
            ax += wr[c] * t.x; ay += wr[c] * t.y; az += wr[c] * t.z; aw += wr[c] * t.w;
        }
        o4[i] = make_float4(ax, ay, az, aw);
        atomicAdd(&h[f2key(ax) >> 20], 1u);
        atomicAdd(&h[f2key(ay) >> 20], 1u);
        atomicAdd(&h[f2key(az) >> 20], 1u);
        atomicAdd(&h[f2key(aw) >> 20], 1u);
    }
    __syncthreads();
    uint32_t* dst = slice + (size_t)blockIdx.x * 4096;
    for (int i = threadIdx.x; i < 4096; i += 256) dst[i] = h[i];
}

__global__ __launch_bounds__(256) void reduce1_kernel(const uint32_t* __restrict__ slice,
        uint32_t* __restrict__ meta) {
    int tid = blockIdx.x * 256 + threadIdx.x;
    int bin = tid & 4095;
    int chunk = tid >> 12;
    uint32_t sum = 0;
    for (int j = chunk * 64; j < chunk * 64 + 64; ++j)
        sum += slice[(size_t)j * 4096 + bin];
    if (sum) atomicAdd(&meta[M_HIST1 + bin], sum);
}

__global__ __launch_bounds__(256) void select1_kernel(uint32_t* __restrict__ meta) {
    __shared__ uint32_t hl[4096];
    __shared__ uint32_t sc[256];
    select_bin(meta + M_HIST1, 4096, K0_RANK, hl, sc, meta + M_SEL);
}

// ---------------------------------------------------------------------------
// 2) fused mask + candidate collection (block-aggregated append)
// ---------------------------------------------------------------------------
__global__ __launch_bounds__(256) void maskcollect_kernel(const float* __restrict__ agg,
        uint32_t* __restrict__ meta, uint32_t* __restrict__ B,
        float* __restrict__ candV, uint32_t* __restrict__ candC) {
    __shared__ float vals[64][64];
    __shared__ uint32_t tile[64][2];
    __shared__ uint32_t wcnt[4];
    __shared__ uint32_t wmn[4];
    __shared__ uint32_t baseSh;
    const uint32_t b1 = meta[M_SEL + 0];
    int u0 = blockIdx.x * 64, v0 = blockIdx.y * 64;
    int wave = threadIdx.x >> 6, lane = threadIdx.x & 63;
    uint32_t mn = 0xFFFFFFFFu;
    uint32_t bndbits = 0;
    int cnt_t = 0;
    for (int i = 0; i < 16; ++i) {
        int r = wave * 16 + i;
        int u = u0 + r, v = v0 + lane;
        float val = agg[(int64_t)u * N_NODES + v];
        vals[r][lane] = val;
        uint32_t key = f2key(val);
        uint32_t hi = key >> 20;
        bool sure = (hi > b1) || (u == v);
        if (hi > b1) mn = min(mn, key);
        unsigned long long bm = __ballot(sure ? 1 : 0);
        if (lane == 0) { tile[r][0] = (uint32_t)bm; tile[r][1] = (uint32_t)(bm >> 32); }
        if (hi == b1) { bndbits |= (1u << i); ++cnt_t; }
    }
    int sc = cnt_t;
#pragma unroll
    for (int d = 1; d < 64; d <<= 1) {
        int a = __shfl_up(sc, d);
        if (lane >= d) sc += a;
    }
    if (lane == 63) wcnt[wave] = (uint32_t)sc;
#pragma unroll
    for (int o = 1; o < 64; o <<= 1) {
        uint32_t other = (uint32_t)__shfl_xor((int)mn, o);
        mn = min(mn, other);
    }
    if (lane == 0) wmn[wave] = mn;
    __syncthreads();
    if (threadIdx.x == 0) {
        uint32_t tot = wcnt[0] + wcnt[1] + wcnt[2] + wcnt[3];
        baseSh = tot ? atomicAdd(&meta[M_CNT], tot) : 0u;
        uint32_t m = min(min(wmn[0], wmn[1]), min(wmn[2], wmn[3]));
        if (m != 0xFFFFFFFFu) atomicMax(&meta[M_MXB], ~m);
    }
    __syncthreads();
    uint32_t wbase = 0;
    for (int wv = 0; wv < wave; ++wv) wbase += wcnt[wv];
    uint32_t p = baseSh + wbase + (uint32_t)(sc - cnt_t);
    uint32_t m = bndbits;
    while (m) {
        int i = __ffs(m) - 1; m &= m - 1;
        int r = wave * 16 + i;
        candV[p] = vals[r][lane];
        candC[p] = ((uint32_t)(u0 + r) << 12) | (uint32_t)(v0 + lane);
        ++p;
    }
    int t = threadIdx.x;
    if (t < 64) {
        int v = v0 + t;
        int sh = t & 31, hw = t >> 5;
        uint32_t w0 = 0, w1 = 0;
#pragma unroll
        for (int i = 0; i < 32; ++i) {
            w0 |= ((tile[i][hw] >> sh) & 1u) << i;
            w1 |= ((tile[32 + i][hw] >> sh) & 1u) << i;
        }
        B[(int64_t)v * (N_NODES / 32) + (u0 >> 5)]     = w0;
        B[(int64_t)v * (N_NODES / 32) + (u0 >> 5) + 1] = w1;
        uint32_t d = (uint32_t)(__popc(w0) + __popc(w1));
        if (d) atomicAdd(&meta[M_DEG + v], d);
    }
}

__global__ __launch_bounds__(256) void histA_kernel(const float* __restrict__ candV,
        uint32_t* __restrict__ meta) {
    __shared__ uint32_t h[4096];
    for (int i = threadIdx.x; i < 4096; i += 256) h[i] = 0;
    uint32_t n = meta[M_CNT];
    __syncthreads();
    for (uint32_t i = blockIdx.x * 256 + threadIdx.x; i < n; i += 64 * 256) {
        uint32_t k = f2key(candV[i]);
        atomicAdd(&h[(k >> 8) & 0xFFFu], 1u);
    }
    __syncthreads();
    for (int i = threadIdx.x; i < 4096; i += 256) {
        uint32_t c = h[i];
        if (c) atomicAdd(&meta[M_HISTA + i], c);
    }
}

__global__ __launch_bounds__(256) void select2_kernel(uint32_t* __restrict__ meta) {
    __shared__ uint32_t hl[4096];
    __shared__ uint32_t sc[256];
    uint32_t r1 = meta[M_SEL + 1];
    __syncthreads();
    select_bin(meta + M_HISTA, 4096, r1, hl, sc, meta + M_SEL + 2);
}

__global__ __launch_bounds__(256) void collect2_kernel(const float* __restrict__ candV,
        uint32_t* __restrict__ meta) {
    __shared__ uint32_t hB[256];
    __shared__ uint32_t wmn[4];
    hB[threadIdx.x] = 0;
    uint32_t b2 = meta[M_SEL + 2];
    uint32_t n = meta[M_CNT];
    __syncthreads();
    uint32_t mn = 0xFFFFFFFFu;
    for (uint32_t i = blockIdx.x * 256 + threadIdx.x; i < n; i += 64 * 256) {
        uint32_t key = f2key(candV[i]);
        uint32_t sub = (key >> 8) & 0xFFFu;
        if (sub == b2) atomicAdd(&hB[key & 0xFFu], 1u);
        else if (sub > b2) mn = min(mn, key);
    }
#pragma unroll
    for (int o = 1; o < 64; o <<= 1) {
        uint32_t other = (uint32_t)__shfl_xor((int)mn, o);
        mn = min(mn, other);
    }
    if ((threadIdx.x & 63) == 0) wmn[threadIdx.x >> 6] = mn;
    __syncthreads();
    if (threadIdx.x == 0) {
        uint32_t m = min(min(wmn[0], wmn[1]), min(wmn[2], wmn[3]));
        if (m != 0xFFFFFFFFu) atomicMax(&meta[M_MXS], ~m);
    }
    uint32_t c = hB[threadIdx.x];
    if (c) atomicAdd(&meta[M_HISTB + threadIdx.x], c);
}

__global__ void select3_kernel(uint32_t* __restrict__ meta) {
    __shared__ uint32_t h[256];
    h[threadIdx.x] = meta[M_HISTB + threadIdx.x];
    __syncthreads();
    if (threadIdx.x == 0) {
        uint32_t b1 = meta[M_SEL + 0], b2 = meta[M_SEL + 2], r2 = meta[M_SEL + 3];
        uint32_t cum = 0; int b = 0;
        while (cum + h[b] <= r2) { cum += h[b]; ++b; }
        uint32_t key0 = (b1 << 20) | (b2 << 8) | (uint32_t)b;
        uint32_t cle = cum + h[b];
        uint32_t key1;
        if (cle >= r2 + 2u) key1 = key0;
        else {
            int nb = b + 1;
            while (nb < 256 && h[nb] == 0) ++nb;
            if (nb < 256) key1 = (b1 << 20) | (b2 << 8) | (uint32_t)nb;
            else {
                uint32_t ks = ~meta[M_MXS];
                key1 = (ks != 0xFFFFFFFFu) ? ks : ~meta[M_MXB];
            }
        }
        float v0 = key2f(key0);
        float v1 = key2f(key1);
        ((float*)meta)[M_SEL + 7] = v0 + 0.5f * (v1 - v0);
    }
}

__global__ __launch_bounds__(256) void fixup_kernel(const float* __restrict__ candV,
        const uint32_t* __restrict__ candC, uint32_t* __restrict__ meta,
        uint32_t* __restrict__ B) {
    uint32_t n = meta[M_CNT];
    float th = ((const float*)meta)[M_SEL + 7];
    for (uint32_t i = blockIdx.x * 256 + threadIdx.x; i < n; i += 128 * 256) {
        if (candV[i] >= th) {
            uint32_t c = candC[i];
            uint32_t u = c >> 12, v = c & 0xFFFu;
            uint32_t bit = 1u << (u & 31u);
            uint32_t old = atomicOr(&B[(int64_t)v * 128 + (u >> 5)], bit);
            if (!(old & bit)) atomicAdd(&meta[M_DEG + v], 1u);
        }
    }
}

// ---------------------------------------------------------------------------
// 3) gemm1: g = s_u*(x@W1); emit transposed bf16 hi/lo  G1T[ch][u]
// ---------------------------------------------------------------------------
__global__ __launch_bounds__(256) void gemm1_kernel(const float* __restrict__ x,
        const float* __restrict__ W1, const uint32_t* __restrict__ deg,
        ushort* __restrict__ G1H, ushort* __restrict__ G1L) {
    __shared__ float xr[8 * 128];
    __shared__ float sr[8];
    int u0 = blockIdx.x * 8;
    int t = threadIdx.x;
    ((float4*)xr)[t] = ((const float4*)(x + (int64_t)u0 * 128))[t];
    if (t < 8) sr[t] = rsqrtf((float)deg[u0 + t]);
    __syncthreads();
    float acc[8] = {0, 0, 0, 0, 0, 0, 0, 0};
    for (int k = 0; k < 128; k += 4) {
        float w0 = W1[(k + 0) * 256 + t], w1 = W1[(k + 1) * 256 + t];
        float w2 = W1[(k + 2) * 256 + t], w3 = W1[(k + 3) * 256 + t];
#pragma unroll
        for (int r = 0; r < 8; ++r) {
            float4 xv = *(const float4*)&xr[r * 128 + k];
            acc[r] += xv.x * w0 + xv.y * w1 + xv.z * w2 + xv.w * w3;
        }
    }
    short8v hi8, lo8;
#pragma unroll
    for (int r = 0; r < 8; ++r) {
        float gv = sr[r] * acc[r];
        ushort h = f2bf(gv);
        ushort l = f2bf(gv - bf2f(h));
        hi8[r] = (short)h;
        lo8[r] = (short)l;
    }
    *(short8v*)(G1H + (int64_t)t * 4096 + u0) = hi8;
    *(short8v*)(G1L + (int64_t)t * 4096 + u0) = lo8;
}

// ---------------------------------------------------------------------------
// 4) spmm1 via MFMA: h1[v][ch] = relu(s_v * sum_u M[v][u]*(Ghi+Glo)[u][ch] + b1)
//    grid: (128 v-tiles of 32) x (2 ch-halves of 128); 4 waves, wave = 2m x 2n
// ---------------------------------------------------------------------------
__global__ __launch_bounds__(256) void spmm1_mfma(const uint32_t* __restrict__ B,
        const ushort* __restrict__ GH, const ushort* __restrict__ GL,
        const uint32_t* __restrict__ deg, const float* __restrict__ b1,
        float* __restrict__ h1) {
    __shared__ uint32_t Blds[32][129];
    int v0 = (blockIdx.x >> 1) * 32;
    int chh = blockIdx.x & 1;
    int t = threadIdx.x, wave = t >> 6, lane = t & 63;
    for (int i = t; i < 32 * 128; i += 256)
        Blds[i >> 7][i & 127] = B[(int64_t)(v0 + (i >> 7)) * 128 + (i & 127)];
    __syncthreads();
    int n_base = chh * 128 + wave * 32;
    int lr = lane & 15, lg = lane >> 4;
    const ushort* gh0 = GH + (int64_t)(n_base + lr) * 4096;
    const ushort* gh1 = GH + (int64_t)(n_base + 16 + lr) * 4096;
    const ushort* gl0 = GL + (int64_t)(n_base + lr) * 4096;
    const ushort* gl1 = GL + (int64_t)(n_base + 16 + lr) * 4096;
    f32x4 acc00 = {0,0,0,0}, acc01 = {0,0,0,0}, acc10 = {0,0,0,0}, acc11 = {0,0,0,0};
#pragma unroll 2
    for (int c = 0; c < 128; ++c) {
        int u8 = c * 32 + lg * 8;
        short8v bh0 = *(const short8v*)(gh0 + u8);
        short8v bh1 = *(const short8v*)(gh1 + u8);
        short8v bl0 = *(const short8v*)(gl0 + u8);
        short8v bl1 = *(const short8v*)(gl1 + u8);
        uint32_t by0 = (Blds[lr][c] >> (lg * 8)) & 0xFFu;
        uint32_t by1 = (Blds[16 + lr][c] >> (lg * 8)) & 0xFFu;
        short8v a0, a1;
#pragma unroll
        for (int j = 0; j < 8; ++j) {
            a0[j] = (short)(((by0 >> j) & 1u) ? 0x3F80 : 0);
            a1[j] = (short)(((by1 >> j) & 1u) ? 0x3F80 : 0);
        }
        acc00 = __builtin_amdgcn_mfma_f32_16x16x32_bf16(a0, bh0, acc00, 0, 0, 0);
        acc01 = __builtin_amdgcn_mfma_f32_16x16x32_bf16(a0, bh1, acc01, 0, 0, 0);
        acc10 = __builtin_amdgcn_mfma_f32_16x16x32_bf16(a1, bh0, acc10, 0, 0, 0);
        acc11 = __builtin_amdgcn_mfma_f32_16x16x32_bf16(a1, bh1, acc11, 0, 0, 0);
        acc00 = __builtin_amdgcn_mfma_f32_16x16x32_bf16(a0, bl0, acc00, 0, 0, 0);
        acc01 = __builtin_amdgcn_mfma_f32_16x16x32_bf16(a0, bl1, acc01, 0, 0, 0);
        acc10 = __builtin_amdgcn_mfma_f32_16x16x32_bf16(a1, bl0, acc10, 0, 0, 0);
        acc11 = __builtin_amdgcn_mfma_f32_16x16x32_bf16(a1, bl1, acc11, 0, 0, 0);
    }
#pragma unroll
    for (int q = 0; q < 4; ++q) {
        int vr0 = v0 + lg * 4 + q;        // mi = 0
        int vr1 = vr0 + 16;               // mi = 1
        float sv0 = rsqrtf((float)deg[vr0]);
        float sv1 = rsqrtf((float)deg[vr1]);
        int c0 = n_base + lr, c1 = n_base + 16 + lr;
        h1[(int64_t)vr0 * 256 + c0] = fmaxf(sv0 * acc00[q] + b1[c0], 0.f);
        h1[(int64_t)vr0 * 256 + c1] = fmaxf(sv0 * acc01[q] + b1[c1], 0.f);
        h1[(int64_t)vr1 * 256 + c0] = fmaxf(sv1 * acc10[q] + b1[c0], 0.f);
        h1[(int64_t)vr1 * 256 + c1] = fmaxf(sv1 * acc11[q] + b1[c1], 0.f);
    }
}

// ---------------------------------------------------------------------------
// 5) gemm2: g2 = s_u*(h1@W2); emit transposed bf16 hi/lo  G2T[ch][u]
// ---------------------------------------------------------------------------
__global__ __launch_bounds__(256) void gemm2_kernel(const float* __restrict__ h1,
        const float* __restrict__ W2, const uint32_t* __restrict__ deg,
        ushort* __restrict__ G2H, ushort* __restrict__ G2L) {
    __shared__ float hr[8 * 256];
    __shared__ float sr[8];
    int u0 = blockIdx.x * 8;
    int t = threadIdx.x;
    const float4* h4 = (const float4*)(h1 + (int64_t)u0 * 256);
    ((float4*)hr)[t] = h4[t];
    ((float4*)hr)[t + 256] = h4[t + 256];
    if (t < 8) sr[t] = rsqrtf((float)deg[u0 + t]);
    __syncthreads();
    int col = t & 127;
    int roff = (t >> 7) * 4;
    float acc[4] = {0, 0, 0, 0};
    for (int k = 0; k < 256; k += 4) {
        float w0 = W2[(k + 0) * 128 + col], w1 = W2[(k + 1) * 128 + col];
        float w2 = W2[(k + 2) * 128 + col], w3 = W2[(k + 3) * 128 + col];
#pragma unroll
        for (int r = 0; r < 4; ++r) {
            float4 hv = *(const float4*)&hr[(roff + r) * 256 + k];
            acc[r] += hv.x * w0 + hv.y * w1 + hv.z * w2 + hv.w * w3;
        }
    }
    short4v hi4, lo4;
#pragma unroll
    for (int r = 0; r < 4; ++r) {
        float gv = sr[roff + r] * acc[r];
        ushort h = f2bf(gv);
        ushort l = f2bf(gv - bf2f(h));
        hi4[r] = (short)h;
        lo4[r] = (short)l;
    }
    *(short4v*)(G2H + (int64_t)col * 4096 + u0 + roff) = hi4;
    *(short4v*)(G2L + (int64_t)col * 4096 + u0 + roff) = lo4;
}

// ---------------------------------------------------------------------------
// 6) spmm2 via MFMA: out[v][ch] = s_v * sum_u M[v][u]*(G2hi+G2lo)[u][ch] + b2
//    grid: 128 v-tiles of 32; 4 waves cover ch 0..127 (wave*32), wave = 2m x 2n
// ---------------------------------------------------------------------------
__global__ __launch_bounds__(256) void spmm2_mfma(const uint32_t* __restrict__ B,
        const ushort* __restrict__ GH, const ushort* __restrict__ GL,
        const uint32_t* __restrict__ deg, const float* __restrict__ b2,
        float* __restrict__ out) {
    __shared__ uint32_t Blds[32][129];
    int v0 = blockIdx.x * 32;
    int t = threadIdx.x, wave = t >> 6, lane = t & 63;
    for (int i = t; i < 32 * 128; i += 256)
        Blds[i >> 7][i & 127] = B[(int64_t)(v0 + (i >> 7)) * 128 + (i & 127)];
    __syncthreads();
    int n_base = wave * 32;
    int lr = lane & 15, lg = lane >> 4;
    const ushort* gh0 = GH + (int64_t)(n_base + lr) * 4096;
    const ushort* gh1 = GH + (int64_t)(n_base + 16 + lr) * 4096;
    const ushort* gl0 = GL + (int64_t)(n_base + lr) * 4096;
    const ushort* gl1 = GL + (int64_t)(n_base + 16 + lr) * 4096;
    f32x4 acc00 = {0,0,0,0}, acc01 = {0,0,0,0}, acc10 = {0,0,0,0}, acc11 = {0,0,0,0};
#pragma unroll 2
    for (int c = 0; c < 128; ++c) {
        int u8 = c * 32 + lg * 8;
        short8v bh0 = *(const short8v*)(gh0 + u8);
        short8v bh1 = *(const short8v*)(gh1 + u8);
        short8v bl0 = *(const short8v*)(gl0 + u8);
        short8v bl1 = *(const short8v*)(gl1 + u8);
        uint32_t by0 = (Blds[lr][c] >> (lg * 8)) & 0xFFu;
        uint32_t by1 = (Blds[16 + lr][c] >> (lg * 8)) & 0xFFu;
        short8v a0, a1;
#pragma unroll
        for (int j = 0; j < 8; ++j) {
            a0[j] = (short)(((by0 >> j) & 1u) ? 0x3F80 : 0);
            a1[j] = (short)(((by1 >> j) & 1u) ? 0x3F80 : 0);
        }
        acc00 = __builtin_amdgcn_mfma_f32_16x16x32_bf16(a0, bh0, acc00, 0, 0, 0);
        acc01 = __builtin_amdgcn_mfma_f32_16x16x32_bf16(a0, bh1, acc01, 0, 0, 0);
        acc10 = __builtin_amdgcn_mfma_f32_16x16x32_bf16(a1, bh0, acc10, 0, 0, 0);
        acc11 = __builtin_amdgcn_mfma_f32_16x16x32_bf16(a1, bh1, acc11, 0, 0, 0);
        acc00 = __builtin_amdgcn_mfma_f32_16x16x32_bf16(a0, bl0, acc00, 0, 0, 0);
        acc01 = __builtin_amdgcn_mfma_f32_16x16x32_bf16(a0, bl1, acc01, 0, 0, 0);
        acc10 = __builtin_amdgcn_mfma_f32_16x16x32_bf16(a1, bl0, acc10, 0, 0, 0);
        acc11 = __builtin_amdgcn_mfma_f32_16x16x32_bf16(a1, bl1, acc11, 0, 0, 0);
    }
#pragma unroll
    for (int q = 0; q < 4; ++q) {
        int vr0 = v0 + lg * 4 + q;
        int vr1 = vr0 + 16;
        float sv0 = rsqrtf((float)deg[vr0]);
        float sv1 = rsqrtf((float)deg[vr1]);
        int c0 = n_base + lr, c1 = n_base + 16 + lr;
        out[(int64_t)vr0 * 128 + c0] = sv0 * acc00[q] + b2[c0];
        out[(int64_t)vr0 * 128 + c1] = sv0 * acc01[q] + b2[c1];
        out[(int64_t)vr1 * 128 + c0] = sv1 * acc10[q] + b2[c0];
        out[(int64_t)vr1 * 128 + c1] = sv1 * acc11[q] + b2[c1];
    }
}

// ---------------------------------------------------------------------------
extern "C" void kernel_launch(void* const* d_in, const int* in_sizes, int n_in,
                              void* d_out, int out_size, void* d_ws, size_t ws_size,
                              hipStream_t stream) {
    const float* x    = (const float*)d_in[0];
    const float* attn = (const float*)d_in[1];
    const float* aggw = (const float*)d_in[2];
    const float* aggb = (const float*)d_in[3];
    const float* W1   = (const float*)d_in[4];
    const float* b1   = (const float*)d_in[5];
    const float* W2   = (const float*)d_in[6];
    const float* b2   = (const float*)d_in[7];
    float* out = (float*)d_out;

    char* ws = (char*)d_ws;
    size_t OFF_AGG   = 0;
    size_t OFF_SLICE = OFF_AGG + (size_t)NNN * 4;
    size_t OFF_META  = OFF_SLICE + (size_t)1024 * 4096 * 4;
    size_t OFF_B     = OFF_META + (size_t)M_WORDS * 4 + 256;
    size_t OFF_CV    = OFF_B + (size_t)N_NODES * (N_NODES / 32) * 4;
    size_t OFF_CC    = OFF_CV + (size_t)NNN * 4;
    size_t OFF_G1H   = OFF_CC + (size_t)NNN * 4;
    size_t OFF_G1L   = OFF_G1H + (size_t)256 * 4096 * 2;
    size_t OFF_H1    = OFF_G1L + (size_t)256 * 4096 * 2;
    size_t OFF_G2H   = OFF_H1 + (size_t)N_NODES * 256 * 4;
    size_t OFF_G2L   = OFF_G2H + (size_t)128 * 4096 * 2;

    float*    agg   = (float*)(ws + OFF_AGG);
    uint32_t* slice = (uint32_t*)(ws + OFF_SLICE);
    uint32_t* meta  = (uint32_t*)(ws + OFF_META);
    uint32_t* Bm    = (uint32_t*)(ws + OFF_B);
    float*    candV = (float*)(ws + OFF_CV);
    uint32_t* candC = (uint32_t*)(ws + OFF_CC);
    ushort*   G1H   = (ushort*)(ws + OFF_G1H);
    ushort*   G1L   = (ushort*)(ws + OFF_G1L);
    float*    h1    = (float*)(ws + OFF_H1);
    ushort*   G2H   = (ushort*)(ws + OFF_G2H);
    ushort*   G2L   = (ushort*)(ws + OFF_G2L);
    uint32_t* deg   = meta + M_DEG;

    agg_kernel<<<1024, 256, 0, stream>>>(attn, aggw, aggb, agg, slice, meta);
    reduce1_kernel<<<256, 256, 0, stream>>>(slice, meta);
    select1_kernel<<<1, 256, 0, stream>>>(meta);
    maskcollect_kernel<<<dim3(64, 64), 256, 0, stream>>>(agg, meta, Bm, candV, candC);
    histA_kernel<<<64, 256, 0, stream>>>(candV, meta);
    select2_kernel<<<1, 256, 0, stream>>>(meta);
    collect2_kernel<<<64, 256, 0, stream>>>(candV, meta);
    select3_kernel<<<1, 256, 0, stream>>>(meta);
    fixup_kernel<<<128, 256, 0, stream>>>(candV, candC, meta, Bm);

    gemm1_kernel<<<512, 256, 0, stream>>>(x, W1, deg, G1H, G1L);
    spmm1_mfma<<<256, 256, 0, stream>>>(Bm, G1H, G1L, deg, b1, h1);
    gemm2_kernel<<<512, 256, 0, stream>>>(h1, W2, deg, G2H, G2L);
    spmm2_mfma<<<128, 256, 0, stream>>>(Bm, G2H, G2L, deg, b2, out);
}

// Round 7
// 411.602 us; speedup vs baseline: 1.2230x; 1.2230x over previous
//
#include <hip/hip_runtime.h>
#include <stdint.h>

#define N_NODES 4096
#define NNN ((int64_t)N_NODES * (int64_t)N_NODES)
#define TOTAL4 (NNN / 4)
#define NC 12
// floor(0.9 * (N*N - 1)) = 15099493 (frac = 0.5)
#define K0_RANK 15099493u

// META layout (u32 words)
#define M_HIST1 0
#define M_HISTA 4096
#define M_HISTB 8192
#define M_DEG   8448
#define M_MXB   12544   // atomicMax of ~key over keys in bins > b1
#define M_MXS   12545   // atomicMax of ~key over keys in sub-bins > b2 (within b1)
#define M_SEL   12552   // [0]=b1 [1]=r1 [2]=b2 [3]=r2 [7]=thresh(float)
#define M_CNTS  12800   // 1024 per-block candidate counts
#define M_WORDS 14336   // zeroed region (56 blocks x 256)

#define CHUNK_V 16384   // values per collect block (= 4096 float4)

static __device__ __forceinline__ uint32_t f2key(float f) {
    uint32_t x = __float_as_uint(f);
    return (x & 0x80000000u) ? ~x : (x | 0x80000000u);
}
static __device__ __forceinline__ float key2f(uint32_t k) {
    uint32_t x = (k & 0x80000000u) ? (k & 0x7FFFFFFFu) : ~k;
    return __uint_as_float(x);
}

// 256-thread block-wide select over nb-bin histogram -> out[0]=bin, out[1]=rank
static __device__ __forceinline__ void select_bin(const uint32_t* __restrict__ gh,
        int nb, uint32_t target, uint32_t* hl, uint32_t* sc, uint32_t* out) {
    int t = threadIdx.x;
    int per = nb >> 8;
    for (int i = t; i < nb; i += 256) hl[i] = gh[i];
    __syncthreads();
    uint32_t p = 0;
    for (int i = 0; i < per; ++i) p += hl[t * per + i];
    sc[t] = p;
    __syncthreads();
    for (int d = 1; d < 256; d <<= 1) {
        uint32_t v = (t >= d) ? sc[t - d] : 0u;
        __syncthreads();
        sc[t] += v;
        __syncthreads();
    }
    uint32_t excl = sc[t] - p;
    if (p > 0 && target >= excl && target < excl + p) {
        uint32_t cum = excl; int b = t * per;
        while (cum + hl[b] <= target) { cum += hl[b]; ++b; }
        out[0] = (uint32_t)b; out[1] = target - cum;
    }
    __syncthreads();
}

// ---------------------------------------------------------------------------
// 1) agg = sum_c w[c]*attn[c] + b ; per-block hist slice; zero META
// ---------------------------------------------------------------------------
__global__ __launch_bounds__(256) void agg_kernel(const float* __restrict__ attn,
        const float* __restrict__ w, const float* __restrict__ bb,
        float* __restrict__ agg, uint32_t* __restrict__ slice,
        uint32_t* __restrict__ meta) {
    if (blockIdx.x < 56) meta[blockIdx.x * 256 + threadIdx.x] = 0;
    __shared__ uint32_t h[4096];
    for (int i = threadIdx.x; i < 4096; i += 256) h[i] = 0;
    float wr[NC];
#pragma unroll
    for (int c = 0; c < NC; ++c) wr[c] = w[c];
    float b0 = bb[0];
    __syncthreads();
    const float4* a4 = (const float4*)attn;
    float4* o4 = (float4*)agg;
    for (int64_t i = (int64_t)blockIdx.x * 256 + threadIdx.x; i < TOTAL4; i += (int64_t)1024 * 256) {
        float ax = b0, ay = b0, az = b0, aw = b0;
#pragma unroll
        for (int c = 0; c < NC; ++c) {
            float4 t = a4[(int64_t)c * TOTAL4 + i];
            ax += wr[c] * t.x; ay += wr[c] * t.y; az += wr[c] * t.z; aw += wr[c] * t.w;
        }
        o4[i] = make_float4(ax, ay, az, aw);
        atomicAdd(&h[f2key(ax) >> 20], 1u);
        atomicAdd(&h[f2key(ay) >> 20], 1u);
        atomicAdd(&h[f2key(az) >> 20], 1u);
        atomicAdd(&h[f2key(aw) >> 20], 1u);
    }
    __syncthreads();
    uint32_t* dst = slice + (size_t)blockIdx.x * 4096;
    for (int i = threadIdx.x; i < 4096; i += 256) dst[i] = h[i];
}

// reduce the 1024 slices -> hist1
__global__ __launch_bounds__(256) void reduce1_kernel(const uint32_t* __restrict__ slice,
        uint32_t* __restrict__ meta) {
    int tid = blockIdx.x * 256 + threadIdx.x;
    int bin = tid & 4095;
    int chunk = tid >> 12;
    uint32_t sum = 0;
    for (int j = chunk * 64; j < chunk * 64 + 64; ++j)
        sum += slice[(size_t)j * 4096 + bin];
    if (sum) atomicAdd(&meta[M_HIST1 + bin], sum);
}

// ---------------------------------------------------------------------------
// 2) collect: inline select1; stream agg; compact b1-bin values into per-block
//    region; fused histA (bits 19..8) in LDS; track min key above b1.
// ---------------------------------------------------------------------------
__global__ __launch_bounds__(256) void collect_kernel(const float* __restrict__ agg,
        uint32_t* __restrict__ meta, float* __restrict__ candV) {
    __shared__ uint32_t hl[4096];
    __shared__ uint32_t sc[256];
    __shared__ uint32_t res[2];
    __shared__ uint32_t cnt, ms;
    int t = threadIdx.x;
    select_bin(meta + M_HIST1, 4096, K0_RANK, hl, sc, res);
    uint32_t b1 = res[0];
    if (t == 0) {
        meta[M_SEL + 0] = res[0]; meta[M_SEL + 1] = res[1];   // same in all blocks
        cnt = 0; ms = 0xFFFFFFFFu;
    }
    for (int i = t; i < 4096; i += 256) hl[i] = 0;            // reuse as histA
    __syncthreads();
    const float4* a4 = (const float4*)agg;
    float* region = candV + (size_t)blockIdx.x * CHUNK_V;
    int64_t base = (int64_t)blockIdx.x * 4096;
    uint32_t mn = 0xFFFFFFFFu;
#define PROCV(val) { uint32_t k = f2key(val); uint32_t hi = k >> 20; \
    if (hi == b1) { uint32_t p = atomicAdd(&cnt, 1u); region[p] = (val); \
                    atomicAdd(&hl[(k >> 8) & 0xFFFu], 1u); } \
    else if (hi > b1) mn = min(mn, k); }
    for (int it = 0; it < 16; ++it) {
        float4 v = a4[base + it * 256 + t];
        PROCV(v.x) PROCV(v.y) PROCV(v.z) PROCV(v.w)
    }
    atomicMin(&ms, mn);
    __syncthreads();
    for (int i = t; i < 4096; i += 256) {
        uint32_t c = hl[i];
        if (c) atomicAdd(&meta[M_HISTA + i], c);
    }
    if (t == 0) {
        meta[M_CNTS + blockIdx.x] = cnt;
        if (ms != 0xFFFFFFFFu) atomicMax(&meta[M_MXB], ~ms);
    }
}

__global__ __launch_bounds__(256) void select2_kernel(uint32_t* __restrict__ meta) {
    __shared__ uint32_t hl[4096];
    __shared__ uint32_t sc[256];
    uint32_t r1 = meta[M_SEL + 1];
    __syncthreads();
    select_bin(meta + M_HISTA, 4096, r1, hl, sc, meta + M_SEL + 2);
}

// refine within sub-bin b2 over per-block candidate regions
__global__ __launch_bounds__(256) void collect2_kernel(const float* __restrict__ candV,
        uint32_t* __restrict__ meta) {
    __shared__ uint32_t hB[256];
    __shared__ uint32_t ms2;
    int t = threadIdx.x;
    hB[t] = 0;
    if (t == 0) ms2 = 0xFFFFFFFFu;
    uint32_t b2 = meta[M_SEL + 2];
    uint32_t n = meta[M_CNTS + blockIdx.x];
    const float* region = candV + (size_t)blockIdx.x * CHUNK_V;
    __syncthreads();
    uint32_t mn = 0xFFFFFFFFu;
    for (uint32_t i = t; i < n; i += 256) {
        uint32_t key = f2key(region[i]);
        uint32_t sub = (key >> 8) & 0xFFFu;
        if (sub == b2) atomicAdd(&hB[key & 0xFFu], 1u);
        else if (sub > b2) mn = min(mn, key);
    }
    atomicMin(&ms2, mn);
    __syncthreads();
    uint32_t c = hB[t];
    if (c) atomicAdd(&meta[M_HISTB + t], c);
    if (t == 0 && ms2 != 0xFFFFFFFFu) atomicMax(&meta[M_MXS], ~ms2);
}

__global__ void select3_kernel(uint32_t* __restrict__ meta) {
    __shared__ uint32_t h[256];
    h[threadIdx.x] = meta[M_HISTB + threadIdx.x];
    __syncthreads();
    if (threadIdx.x == 0) {
        uint32_t b1 = meta[M_SEL + 0], b2 = meta[M_SEL + 2], r2 = meta[M_SEL + 3];
        uint32_t cum = 0; int b = 0;
        while (cum + h[b] <= r2) { cum += h[b]; ++b; }
        uint32_t key0 = (b1 << 20) | (b2 << 8) | (uint32_t)b;
        uint32_t cle = cum + h[b];
        uint32_t key1;
        if (cle >= r2 + 2u) key1 = key0;
        else {
            int nb = b + 1;
            while (nb < 256 && h[nb] == 0) ++nb;
            if (nb < 256) key1 = (b1 << 20) | (b2 << 8) | (uint32_t)nb;
            else {
                uint32_t ks = ~meta[M_MXS];
                key1 = (ks != 0xFFFFFFFFu) ? ks : ~meta[M_MXB];
            }
        }
        float v0 = key2f(key0);
        float v1 = key2f(key1);
        ((float*)meta)[M_SEL + 7] = v0 + 0.5f * (v1 - v0);   // same formula R1-R6
    }
}

// ---------------------------------------------------------------------------
// 3) B[v][u] bitmask of A^T (A = mask | I) + fused deg. x = v-tile (fast) so
//    consecutive blocks share u-rows (HBM locality).
// ---------------------------------------------------------------------------
__global__ __launch_bounds__(256) void maskB_kernel(const float* __restrict__ agg,
        const uint32_t* __restrict__ meta, uint32_t* __restrict__ B,
        uint32_t* __restrict__ deg) {
    __shared__ uint32_t tile[64][2];
    const float thresh = __uint_as_float(meta[M_SEL + 7]);
    int u0 = blockIdx.y * 64, v0 = blockIdx.x * 64;
    int wave = threadIdx.x >> 6, lane = threadIdx.x & 63;
    for (int i = 0; i < 16; ++i) {
        int r = wave * 16 + i;
        int u = u0 + r, v = v0 + lane;
        float val = agg[(int64_t)u * N_NODES + v];
        bool pred = (val >= thresh) || (u == v);
        unsigned long long bm = __ballot(pred ? 1 : 0);
        if (lane == 0) { tile[r][0] = (uint32_t)bm; tile[r][1] = (uint32_t)(bm >> 32); }
    }
    __syncthreads();
    int t = threadIdx.x;
    if (t < 64) {
        int v = v0 + t;
        int sh = t & 31, hw = t >> 5;
        uint32_t w0 = 0, w1 = 0;
#pragma unroll
        for (int i = 0; i < 32; ++i) {
            w0 |= ((tile[i][hw] >> sh) & 1u) << i;
            w1 |= ((tile[32 + i][hw] >> sh) & 1u) << i;
        }
        B[(int64_t)v * (N_NODES / 32) + (u0 >> 5)]     = w0;
        B[(int64_t)v * (N_NODES / 32) + (u0 >> 5) + 1] = w1;
        uint32_t d = (uint32_t)(__popc(w0) + __popc(w1));
        if (d) atomicAdd(&deg[v], d);
    }
}

// ---------------------------------------------------------------------------
// 4) gemms (R3 versions)
// ---------------------------------------------------------------------------
__global__ __launch_bounds__(256) void gemm1_kernel(const float* __restrict__ x,
        const float* __restrict__ W1, const uint32_t* __restrict__ deg,
        float* __restrict__ g) {
    __shared__ float xr[8 * 128];
    __shared__ float sr[8];
    int u0 = blockIdx.x * 8;
    int t = threadIdx.x;
    ((float4*)xr)[t] = ((const float4*)(x + (int64_t)u0 * 128))[t];
    if (t < 8) sr[t] = rsqrtf((float)deg[u0 + t]);
    __syncthreads();
    float acc[8] = {0, 0, 0, 0, 0, 0, 0, 0};
    for (int k = 0; k < 128; k += 4) {
        float w0 = W1[(k + 0) * 256 + t], w1 = W1[(k + 1) * 256 + t];
        float w2 = W1[(k + 2) * 256 + t], w3 = W1[(k + 3) * 256 + t];
#pragma unroll
        for (int r = 0; r < 8; ++r) {
            float4 xv = *(const float4*)&xr[r * 128 + k];
            acc[r] += xv.x * w0 + xv.y * w1 + xv.z * w2 + xv.w * w3;
        }
    }
#pragma unroll
    for (int r = 0; r < 8; ++r)
        g[(int64_t)(u0 + r) * 256 + t] = sr[r] * acc[r];
}

__global__ __launch_bounds__(256) void gemm2_kernel(const float* __restrict__ h1,
        const float* __restrict__ W2, const uint32_t* __restrict__ deg,
        float* __restrict__ g2) {
    __shared__ float hr[8 * 256];
    __shared__ float sr[8];
    int u0 = blockIdx.x * 8;
    int t = threadIdx.x;
    const float4* h4 = (const float4*)(h1 + (int64_t)u0 * 256);
    ((float4*)hr)[t] = h4[t];
    ((float4*)hr)[t + 256] = h4[t + 256];
    if (t < 8) sr[t] = rsqrtf((float)deg[u0 + t]);
    __syncthreads();
    int col = t & 127;
    int roff = (t >> 7) * 4;
    float acc[4] = {0, 0, 0, 0};
    for (int k = 0; k < 256; k += 4) {
        float w0 = W2[(k + 0) * 128 + col], w1 = W2[(k + 1) * 128 + col];
        float w2 = W2[(k + 2) * 128 + col], w3 = W2[(k + 3) * 128 + col];
#pragma unroll
        for (int r = 0; r < 4; ++r) {
            float4 hv = *(const float4*)&hr[(roff + r) * 256 + k];
            acc[r] += hv.x * w0 + hv.y * w1 + hv.z * w2 + hv.w * w3;
        }
    }
#pragma unroll
    for (int r = 0; r < 4; ++r)
        g2[(int64_t)(u0 + roff + r) * 128 + col] = sr[roff + r] * acc[r];
}

// ---------------------------------------------------------------------------
// 5) spmm (R3 versions)
// ---------------------------------------------------------------------------
static __device__ __forceinline__ uint32_t build_idx(const uint32_t* __restrict__ B,
                                                     int v, int t, uint16_t* idx) {
    const uint32_t* row = B + (int64_t)v * 128;
    uint32_t w0 = row[t], w1 = row[t + 64];
    uint32_t pc0 = __popc(w0), pc1 = __popc(w1);
    int s0 = (int)pc0, s1 = (int)pc1;
#pragma unroll
    for (int d = 1; d < 64; d <<= 1) {
        int a = __shfl_up(s0, d);
        int b = __shfl_up(s1, d);
        if (t >= d) { s0 += a; s1 += b; }
    }
    uint32_t tot0 = (uint32_t)__shfl(s0, 63);
    uint32_t cnt  = tot0 + (uint32_t)__shfl(s1, 63);
    uint32_t p = (uint32_t)s0 - pc0;
    uint32_t m = w0;
    int ub = t * 32;
    while (m) { int bi = __ffs(m) - 1; m &= m - 1; idx[p++] = (uint16_t)(ub + bi); }
    p = tot0 + (uint32_t)s1 - pc1;
    m = w1;
    ub = (t + 64) * 32;
    while (m) { int bi = __ffs(m) - 1; m &= m - 1; idx[p++] = (uint16_t)(ub + bi); }
    __syncthreads();
    return cnt;
}

__global__ __launch_bounds__(64) void spmm1_kernel(const uint32_t* __restrict__ B,
        const float* __restrict__ g, const uint32_t* __restrict__ deg,
        const float* __restrict__ b1, float* __restrict__ h1) {
    __shared__ uint16_t idx[4096];
    int v = blockIdx.x;
    int t = threadIdx.x;
    uint32_t cnt = build_idx(B, v, t, idx);
    const float4* g4 = (const float4*)g;
    float4 acc = make_float4(0.f, 0.f, 0.f, 0.f);
    uint32_t i = 0;
    for (; i + 8 <= cnt; i += 8) {
        float4 a0 = g4[idx[i + 0] * 64 + t];
        float4 a1 = g4[idx[i + 1] * 64 + t];
        float4 a2 = g4[idx[i + 2] * 64 + t];
        float4 a3 = g4[idx[i + 3] * 64 + t];
        float4 a4 = g4[idx[i + 4] * 64 + t];
        float4 a5 = g4[idx[i + 5] * 64 + t];
        float4 a6 = g4[idx[i + 6] * 64 + t];
        float4 a7 = g4[idx[i + 7] * 64 + t];
        acc.x += ((a0.x + a1.x) + (a2.x + a3.x)) + ((a4.x + a5.x) + (a6.x + a7.x));
        acc.y += ((a0.y + a1.y) + (a2.y + a3.y)) + ((a4.y + a5.y) + (a6.y + a7.y));
        acc.z += ((a0.z + a1.z) + (a2.z + a3.z)) + ((a4.z + a5.z) + (a6.z + a7.z));
        acc.w += ((a0.w + a1.w) + (a2.w + a3.w)) + ((a4.w + a5.w) + (a6.w + a7.w));
    }
    for (; i < cnt; ++i) {
        float4 a = g4[idx[i] * 64 + t];
        acc.x += a.x; acc.y += a.y; acc.z += a.z; acc.w += a.w;
    }
    float sv = rsqrtf((float)deg[v]);
    float4 bb = ((const float4*)b1)[t];
    float4 r;
    r.x = fmaxf(sv * acc.x + bb.x, 0.f);
    r.y = fmaxf(sv * acc.y + bb.y, 0.f);
    r.z = fmaxf(sv * acc.z + bb.z, 0.f);
    r.w = fmaxf(sv * acc.w + bb.w, 0.f);
    ((float4*)h1)[(int64_t)v * 64 + t] = r;
}

__global__ __launch_bounds__(64) void spmm2_kernel(const uint32_t* __restrict__ B,
        const float* __restrict__ g2, const uint32_t* __restrict__ deg,
        const float* __restrict__ b2, float* __restrict__ out) {
    __shared__ uint16_t idx[4096];
    int v = blockIdx.x;
    int t = threadIdx.x;
    uint32_t cnt = build_idx(B, v, t, idx);
    const float4* g4 = (const float4*)g2;
    int jg = t & 31;
    uint32_t i = (uint32_t)(t >> 5);
    float4 acc = make_float4(0.f, 0.f, 0.f, 0.f);
    for (; i + 6 < cnt; i += 8) {
        float4 a0 = g4[idx[i + 0] * 32 + jg];
        float4 a1 = g4[idx[i + 2] * 32 + jg];
        float4 a2 = g4[idx[i + 4] * 32 + jg];
        float4 a3 = g4[idx[i + 6] * 32 + jg];
        acc.x += (a0.x + a1.x) + (a2.x + a3.x);
        acc.y += (a0.y + a1.y) + (a2.y + a3.y);
        acc.z += (a0.z + a1.z) + (a2.z + a3.z);
        acc.w += (a0.w + a1.w) + (a2.w + a3.w);
    }
    for (; i < cnt; i += 2) {
        float4 a = g4[idx[i] * 32 + jg];
        acc.x += a.x; acc.y += a.y; acc.z += a.z; acc.w += a.w;
    }
    acc.x += __shfl_xor(acc.x, 32);
    acc.y += __shfl_xor(acc.y, 32);
    acc.z += __shfl_xor(acc.z, 32);
    acc.w += __shfl_xor(acc.w, 32);
    if (t < 32) {
        float sv = rsqrtf((float)deg[v]);
        float4 bb = ((const float4*)b2)[jg];
        float4 r;
        r.x = sv * acc.x + bb.x;
        r.y = sv * acc.y + bb.y;
        r.z = sv * acc.z + bb.z;
        r.w = sv * acc.w + bb.w;
        ((float4*)out)[(int64_t)v * 32 + jg] = r;
    }
}

// ---------------------------------------------------------------------------
extern "C" void kernel_launch(void* const* d_in, const int* in_sizes, int n_in,
                              void* d_out, int out_size, void* d_ws, size_t ws_size,
                              hipStream_t stream) {
    const float* x    = (const float*)d_in[0];
    const float* attn = (const float*)d_in[1];
    const float* aggw = (const float*)d_in[2];
    const float* aggb = (const float*)d_in[3];
    const float* W1   = (const float*)d_in[4];
    const float* b1   = (const float*)d_in[5];
    const float* W2   = (const float*)d_in[6];
    const float* b2   = (const float*)d_in[7];
    float* out = (float*)d_out;

    char* ws = (char*)d_ws;
    size_t OFF_AGG   = 0;
    size_t OFF_SLICE = OFF_AGG + (size_t)NNN * 4;                 // 16 MB
    size_t OFF_META  = OFF_SLICE + (size_t)1024 * 4096 * 4;       // 56 KB zeroed
    size_t OFF_B     = OFF_META + (size_t)M_WORDS * 4 + 256;
    size_t OFF_CV    = OFF_B + (size_t)N_NODES * (N_NODES / 32) * 4;  // 64 MB regions
    size_t OFF_G     = OFF_CV + (size_t)1024 * CHUNK_V * 4;
    size_t OFF_H1    = OFF_G + (size_t)N_NODES * 256 * 4;
    size_t OFF_G2    = OFF_H1 + (size_t)N_NODES * 256 * 4;

    float*    agg   = (float*)(ws + OFF_AGG);
    uint32_t* slice = (uint32_t*)(ws + OFF_SLICE);
    uint32_t* meta  = (uint32_t*)(ws + OFF_META);
    uint32_t* Bm    = (uint32_t*)(ws + OFF_B);
    float*    candV = (float*)(ws + OFF_CV);
    float*    g     = (float*)(ws + OFF_G);
    float*    h1    = (float*)(ws + OFF_H1);
    float*    g2    = (float*)(ws + OFF_G2);
    uint32_t* deg   = meta + M_DEG;

    agg_kernel<<<1024, 256, 0, stream>>>(attn, aggw, aggb, agg, slice, meta);
    reduce1_kernel<<<256, 256, 0, stream>>>(slice, meta);
    collect_kernel<<<1024, 256, 0, stream>>>(agg, meta, candV);
    select2_kernel<<<1, 256, 0, stream>>>(meta);
    collect2_kernel<<<1024, 256, 0, stream>>>(candV, meta);
    select3_kernel<<<1, 256, 0, stream>>>(meta);
    maskB_kernel<<<dim3(64, 64), 256, 0, stream>>>(agg, meta, Bm, deg);

    gemm1_kernel<<<512, 256, 0, stream>>>(x, W1, deg, g);
    spmm1_kernel<<<N_NODES, 64, 0, stream>>>(Bm, g, deg, b1, h1);
    gemm2_kernel<<<512, 256, 0, stream>>>(h1, W2, deg, g2);
    spmm2_kernel<<<N_NODES, 64, 0, stream>>>(Bm, g2, deg, b2, out);
}

// Round 8
// 398.477 us; speedup vs baseline: 1.2633x; 1.0329x over previous
//
#include <hip/hip_runtime.h>
#include <stdint.h>

#define N_NODES 4096
#define NNN ((int64_t)N_NODES * (int64_t)N_NODES)
#define TOTAL4 (NNN / 4)
#define NC 12
// floor(0.9 * (N*N - 1)) = 15099493 (frac = 0.5)
#define K0_RANK 15099493u

// META layout (u32 words)
#define M_HIST1 0
#define M_HISTA 4096
#define M_HISTB 8192
#define M_DEG   8448
#define M_MXB   12544   // atomicMax of ~key over keys in bins > b1
#define M_MXS   12545   // atomicMax of ~key over keys in sub-bins > b2 (within b1)
#define M_SEL   12552   // [0]=b1 [1]=r1 [2]=b2 [3]=r2
#define M_CNTS  12800   // 1024 per-block candidate counts
#define M_WORDS 14336   // zeroed region (56 blocks x 256)

#define CHUNK_V 16384   // candidate capacity per collect block (= 4 rows worst case)

typedef __attribute__((ext_vector_type(4))) _Float16 half4v;
typedef __attribute__((ext_vector_type(2))) _Float16 half2v;

static __device__ __forceinline__ uint32_t f2key(float f) {
    uint32_t x = __float_as_uint(f);
    return (x & 0x80000000u) ? ~x : (x | 0x80000000u);
}
static __device__ __forceinline__ float key2f(uint32_t k) {
    uint32_t x = (k & 0x80000000u) ? (k & 0x7FFFFFFFu) : ~k;
    return __uint_as_float(x);
}

// 256-thread block-wide select over nb-bin histogram -> out[0]=bin, out[1]=rank
static __device__ __forceinline__ void select_bin(const uint32_t* __restrict__ gh,
        int nb, uint32_t target, uint32_t* hl, uint32_t* sc, uint32_t* out) {
    int t = threadIdx.x;
    int per = nb >> 8;
    for (int i = t; i < nb; i += 256) hl[i] = gh[i];
    __syncthreads();
    uint32_t p = 0;
    for (int i = 0; i < per; ++i) p += hl[t * per + i];
    sc[t] = p;
    __syncthreads();
    for (int d = 1; d < 256; d <<= 1) {
        uint32_t v = (t >= d) ? sc[t - d] : 0u;
        __syncthreads();
        sc[t] += v;
        __syncthreads();
    }
    uint32_t excl = sc[t] - p;
    if (p > 0 && target >= excl && target < excl + p) {
        uint32_t cum = excl; int b = t * per;
        while (cum + hl[b] <= target) { cum += hl[b]; ++b; }
        out[0] = (uint32_t)b; out[1] = target - cum;
    }
    __syncthreads();
}

// ---------------------------------------------------------------------------
// 1) agg = sum_c w[c]*attn[c] + b ; per-block hist slice; zero META
// ---------------------------------------------------------------------------
__global__ __launch_bounds__(256) void agg_kernel(const float* __restrict__ attn,
        const float* __restrict__ w, const float* __restrict__ bb,
        float* __restrict__ agg, uint32_t* __restrict__ slice,
        uint32_t* __restrict__ meta) {
    if (blockIdx.x < 56) meta[blockIdx.x * 256 + threadIdx.x] = 0;
    __shared__ uint32_t h[4096];
    for (int i = threadIdx.x; i < 4096; i += 256) h[i] = 0;
    float wr[NC];
#pragma unroll
    for (int c = 0; c < NC; ++c) wr[c] = w[c];
    float b0 = bb[0];
    __syncthreads();
    const float4* a4 = (const float4*)attn;
    float4* o4 = (float4*)agg;
    for (int64_t i = (int64_t)blockIdx.x * 256 + threadIdx.x; i < TOTAL4; i += (int64_t)1024 * 256) {
        float ax = b0, ay = b0, az = b0, aw = b0;
#pragma unroll
        for (int c = 0; c < NC; ++c) {
            float4 t = a4[(int64_t)c * TOTAL4 + i];
            ax += wr[c] * t.x; ay += wr[c] * t.y; az += wr[c] * t.z; aw += wr[c] * t.w;
        }
        o4[i] = make_float4(ax, ay, az, aw);
        atomicAdd(&h[f2key(ax) >> 20], 1u);
        atomicAdd(&h[f2key(ay) >> 20], 1u);
        atomicAdd(&h[f2key(az) >> 20], 1u);
        atomicAdd(&h[f2key(aw) >> 20], 1u);
    }
    __syncthreads();
    uint32_t* dst = slice + (size_t)blockIdx.x * 4096;
    for (int i = threadIdx.x; i < 4096; i += 256) dst[i] = h[i];
}

// reduce the 1024 slices -> hist1
__global__ __launch_bounds__(256) void reduce1_kernel(const uint32_t* __restrict__ slice,
        uint32_t* __restrict__ meta) {
    int tid = blockIdx.x * 256 + threadIdx.x;
    int bin = tid & 4095;
    int chunk = tid >> 12;
    uint32_t sum = 0;
    for (int j = chunk * 64; j < chunk * 64 + 64; ++j)
        sum += slice[(size_t)j * 4096 + bin];
    if (sum) atomicAdd(&meta[M_HIST1 + bin], sum);
}

// ---------------------------------------------------------------------------
// 2) collectM: inline select1; stream agg once; emit row-major sure-bit mask M,
//    compact boundary (val, coord), fused histA, min-key-above-b1.
//    Block covers 4 consecutive u-rows (16384 floats).
// ---------------------------------------------------------------------------
__global__ __launch_bounds__(256) void collectM_kernel(const float* __restrict__ agg,
        uint32_t* __restrict__ meta, uint32_t* __restrict__ M,
        float* __restrict__ candV, uint32_t* __restrict__ candC) {
    __shared__ uint32_t hl[4096];
    __shared__ uint32_t sc[256];
    __shared__ uint32_t res[2];
    __shared__ uint32_t mrow[512];
    __shared__ uint32_t cnt, ms;
    int t = threadIdx.x;
    select_bin(meta + M_HIST1, 4096, K0_RANK, hl, sc, res);
    uint32_t b1 = res[0];
    if (t == 0) {
        meta[M_SEL + 0] = res[0]; meta[M_SEL + 1] = res[1];   // same in all blocks
        cnt = 0; ms = 0xFFFFFFFFu;
    }
    for (int i = t; i < 4096; i += 256) hl[i] = 0;            // reuse as histA
    __syncthreads();
    const float4* a4 = (const float4*)agg;
    float*    regV = candV + (size_t)blockIdx.x * CHUNK_V;
    uint32_t* regC = candC + (size_t)blockIdx.x * CHUNK_V;
    int64_t base = (int64_t)blockIdx.x * 4096;     // float4 units
    int u0 = blockIdx.x * 4;
    uint32_t mn = 0xFFFFFFFFu;
    for (int it = 0; it < 16; ++it) {
        int li = it * 256 + t;                      // local float4 idx 0..4095
        float4 v = a4[base + li];
        int u = u0 + (li >> 10);
        int vcol = (li & 1023) * 4;
        float vals[4] = {v.x, v.y, v.z, v.w};
        uint32_t nib = 0;
#pragma unroll
        for (int j = 0; j < 4; ++j) {
            float val = vals[j];
            uint32_t k = f2key(val);
            uint32_t hi = k >> 20;
            if ((hi > b1) || (u == vcol + j)) nib |= (1u << j);
            if (hi > b1) mn = min(mn, k);
            else if (hi == b1) {
                uint32_t p = atomicAdd(&cnt, 1u);
                regV[p] = val;
                regC[p] = ((uint32_t)u << 12) | (uint32_t)(vcol + j);
                atomicAdd(&hl[(k >> 8) & 0xFFFu], 1u);
            }
        }
        // assemble 32-bit mask word across 8 consecutive threads (no atomics)
        uint32_t wd = nib << ((t & 7) * 4);
        wd |= (uint32_t)__shfl_xor((int)wd, 1);
        wd |= (uint32_t)__shfl_xor((int)wd, 2);
        wd |= (uint32_t)__shfl_xor((int)wd, 4);
        if ((t & 7) == 0) mrow[li >> 3] = wd;
    }
    atomicMin(&ms, mn);
    __syncthreads();
    uint32_t* Mdst = M + (size_t)blockIdx.x * 512;   // 4 rows x 128 words
    Mdst[t] = mrow[t];
    Mdst[t + 256] = mrow[t + 256];
    for (int i = t; i < 4096; i += 256) {
        uint32_t c = hl[i];
        if (c) atomicAdd(&meta[M_HISTA + i], c);
    }
    if (t == 0) {
        meta[M_CNTS + blockIdx.x] = cnt;
        if (ms != 0xFFFFFFFFu) atomicMax(&meta[M_MXB], ~ms);
    }
}

// ---------------------------------------------------------------------------
// 3) collect2 (inlined select2): histB over low byte within sub-bin b2 + mgt2
// ---------------------------------------------------------------------------
__global__ __launch_bounds__(256) void collect2_kernel(const float* __restrict__ candV,
        uint32_t* __restrict__ meta) {
    __shared__ uint32_t hl[4096];
    __shared__ uint32_t sc[256];
    __shared__ uint32_t res[2];
    __shared__ uint32_t hB[256];
    __shared__ uint32_t ms2;
    int t = threadIdx.x;
    uint32_t r1 = meta[M_SEL + 1];
    select_bin(meta + M_HISTA, 4096, r1, hl, sc, res);
    uint32_t b2 = res[0];
    hB[t] = 0;
    if (t == 0) {
        ms2 = 0xFFFFFFFFu;
        meta[M_SEL + 2] = res[0]; meta[M_SEL + 3] = res[1];   // same in all blocks
    }
    uint32_t n = meta[M_CNTS + blockIdx.x];
    const float* region = candV + (size_t)blockIdx.x * CHUNK_V;
    __syncthreads();
    uint32_t mn = 0xFFFFFFFFu;
    for (uint32_t i = t; i < n; i += 256) {
        uint32_t key = f2key(region[i]);
        uint32_t sub = (key >> 8) & 0xFFFu;
        if (sub == b2) atomicAdd(&hB[key & 0xFFu], 1u);
        else if (sub > b2) mn = min(mn, key);
    }
    atomicMin(&ms2, mn);
    __syncthreads();
    uint32_t c = hB[t];
    if (c) atomicAdd(&meta[M_HISTB + t], c);
    if (t == 0 && ms2 != 0xFFFFFFFFu) atomicMax(&meta[M_MXS], ~ms2);
}

// ---------------------------------------------------------------------------
// 4) fixupM (inlined select3): compute thresh, patch boundary cands >= thresh
// ---------------------------------------------------------------------------
__global__ __launch_bounds__(256) void fixupM_kernel(const float* __restrict__ candV,
        const uint32_t* __restrict__ candC, const uint32_t* __restrict__ meta,
        uint32_t* __restrict__ M) {
    __shared__ uint32_t h[256];
    __shared__ float thr;
    int t = threadIdx.x;
    h[t] = meta[M_HISTB + t];
    __syncthreads();
    if (t == 0) {
        uint32_t b1 = meta[M_SEL + 0], b2 = meta[M_SEL + 2], r2 = meta[M_SEL + 3];
        uint32_t cum = 0; int b = 0;
        while (cum + h[b] <= r2) { cum += h[b]; ++b; }
        uint32_t key0 = (b1 << 20) | (b2 << 8) | (uint32_t)b;
        uint32_t cle = cum + h[b];
        uint32_t key1;
        if (cle >= r2 + 2u) key1 = key0;
        else {
            int nb = b + 1;
            while (nb < 256 && h[nb] == 0) ++nb;
            if (nb < 256) key1 = (b1 << 20) | (b2 << 8) | (uint32_t)nb;
            else {
                uint32_t ks = ~meta[M_MXS];
                key1 = (ks != 0xFFFFFFFFu) ? ks : ~meta[M_MXB];
            }
        }
        float v0 = key2f(key0);
        float v1 = key2f(key1);
        thr = v0 + 0.5f * (v1 - v0);   // same formula as R1-R7 (verified)
    }
    __syncthreads();
    float th = thr;
    uint32_t n = meta[M_CNTS + blockIdx.x];
    const float*    regV = candV + (size_t)blockIdx.x * CHUNK_V;
    const uint32_t* regC = candC + (size_t)blockIdx.x * CHUNK_V;
    for (uint32_t i = t; i < n; i += 256) {
        if (regV[i] >= th) {
            uint32_t c = regC[i];
            uint32_t u = c >> 12, v = c & 0xFFFu;
            atomicOr(&M[(size_t)u * 128 + (v >> 5)], 1u << (v & 31u));
        }
    }
}

// ---------------------------------------------------------------------------
// 5) transpose bit-matrix M[u][v] -> B[v][u], accumulate deg[v]
// ---------------------------------------------------------------------------
__global__ __launch_bounds__(256) void transposeB_kernel(const uint32_t* __restrict__ M,
        uint32_t* __restrict__ B, uint32_t* __restrict__ deg) {
    __shared__ uint32_t tile[4][64][2];
    int wave = threadIdx.x >> 6, lane = threadIdx.x & 63;
    int tileId = blockIdx.x * 4 + wave;        // 4096 tiles
    int u0 = (tileId & 63) * 64;
    int v0 = (tileId >> 6) * 64;
    uint2 two = *(const uint2*)(M + (size_t)(u0 + lane) * 128 + (v0 >> 5));
    tile[wave][lane][0] = two.x;
    tile[wave][lane][1] = two.y;
    __syncthreads();
    int sh = lane & 31, hw = lane >> 5;
    uint32_t w0 = 0, w1 = 0;
#pragma unroll
    for (int i = 0; i < 32; ++i) {
        w0 |= ((tile[wave][i][hw] >> sh) & 1u) << i;
        w1 |= ((tile[wave][32 + i][hw] >> sh) & 1u) << i;
    }
    B[(size_t)(v0 + lane) * 128 + (u0 >> 5)]     = w0;
    B[(size_t)(v0 + lane) * 128 + (u0 >> 5) + 1] = w1;
    uint32_t d = __popc(w0) + __popc(w1);
    if (d) atomicAdd(&deg[v0 + lane], d);
}

// ---------------------------------------------------------------------------
// 6) gemms: fp32 compute, fp16 transposed-free row-major outputs
// ---------------------------------------------------------------------------
__global__ __launch_bounds__(256) void gemm1_kernel(const float* __restrict__ x,
        const float* __restrict__ W1, const uint32_t* __restrict__ deg,
        _Float16* __restrict__ g) {
    __shared__ float xr[8 * 128];
    __shared__ float sr[8];
    int u0 = blockIdx.x * 8;
    int t = threadIdx.x;
    ((float4*)xr)[t] = ((const float4*)(x + (int64_t)u0 * 128))[t];
    if (t < 8) sr[t] = rsqrtf((float)deg[u0 + t]);
    __syncthreads();
    float acc[8] = {0, 0, 0, 0, 0, 0, 0, 0};
    for (int k = 0; k < 128; k += 4) {
        float w0 = W1[(k + 0) * 256 + t], w1 = W1[(k + 1) * 256 + t];
        float w2 = W1[(k + 2) * 256 + t], w3 = W1[(k + 3) * 256 + t];
#pragma unroll
        for (int r = 0; r < 8; ++r) {
            float4 xv = *(const float4*)&xr[r * 128 + k];
            acc[r] += xv.x * w0 + xv.y * w1 + xv.z * w2 + xv.w * w3;
        }
    }
#pragma unroll
    for (int r = 0; r < 8; ++r)
        g[(int64_t)(u0 + r) * 256 + t] = (_Float16)(sr[r] * acc[r]);
}

__global__ __launch_bounds__(256) void gemm2_kernel(const float* __restrict__ h1,
        const float* __restrict__ W2, const uint32_t* __restrict__ deg,
        _Float16* __restrict__ g2) {
    __shared__ float hr[8 * 256];
    __shared__ float sr[8];
    int u0 = blockIdx.x * 8;
    int t = threadIdx.x;
    const float4* h4 = (const float4*)(h1 + (int64_t)u0 * 256);
    ((float4*)hr)[t] = h4[t];
    ((float4*)hr)[t + 256] = h4[t + 256];
    if (t < 8) sr[t] = rsqrtf((float)deg[u0 + t]);
    __syncthreads();
    int col = t & 127;
    int roff = (t >> 7) * 4;
    float acc[4] = {0, 0, 0, 0};
    for (int k = 0; k < 256; k += 4) {
        float w0 = W2[(k + 0) * 128 + col], w1 = W2[(k + 1) * 128 + col];
        float w2 = W2[(k + 2) * 128 + col], w3 = W2[(k + 3) * 128 + col];
#pragma unroll
        for (int r = 0; r < 4; ++r) {
            float4 hv = *(const float4*)&hr[(roff + r) * 256 + k];
            acc[r] += hv.x * w0 + hv.y * w1 + hv.z * w2 + hv.w * w3;
        }
    }
#pragma unroll
    for (int r = 0; r < 4; ++r)
        g2[(int64_t)(u0 + roff + r) * 128 + col] = (_Float16)(sr[roff + r] * acc[r]);
}

// ---------------------------------------------------------------------------
// 7) spmm: decode bitmask once into LDS idx list, then fp16 row gathers
// ---------------------------------------------------------------------------
static __device__ __forceinline__ uint32_t build_idx(const uint32_t* __restrict__ B,
                                                     int v, int t, uint16_t* idx) {
    const uint32_t* row = B + (int64_t)v * 128;
    uint32_t w0 = row[t], w1 = row[t + 64];
    uint32_t pc0 = __popc(w0), pc1 = __popc(w1);
    int s0 = (int)pc0, s1 = (int)pc1;
#pragma unroll
    for (int d = 1; d < 64; d <<= 1) {
        int a = __shfl_up(s0, d);
        int b = __shfl_up(s1, d);
        if (t >= d) { s0 += a; s1 += b; }
    }
    uint32_t tot0 = (uint32_t)__shfl(s0, 63);
    uint32_t cnt  = tot0 + (uint32_t)__shfl(s1, 63);
    uint32_t p = (uint32_t)s0 - pc0;
    uint32_t m = w0;
    int ub = t * 32;
    while (m) { int bi = __ffs(m) - 1; m &= m - 1; idx[p++] = (uint16_t)(ub + bi); }
    p = tot0 + (uint32_t)s1 - pc1;
    m = w1;
    ub = (t + 64) * 32;
    while (m) { int bi = __ffs(m) - 1; m &= m - 1; idx[p++] = (uint16_t)(ub + bi); }
    __syncthreads();
    return cnt;
}

__global__ __launch_bounds__(64) void spmm1_kernel(const uint32_t* __restrict__ B,
        const _Float16* __restrict__ g, const uint32_t* __restrict__ deg,
        const float* __restrict__ b1, float* __restrict__ h1) {
    __shared__ uint16_t idx[4096];
    int v = blockIdx.x;
    int t = threadIdx.x;
    uint32_t cnt = build_idx(B, v, t, idx);
    const half4v* g4 = (const half4v*)g;      // row = 64 half4
    float4 acc = make_float4(0.f, 0.f, 0.f, 0.f);
    uint32_t i = 0;
    for (; i + 8 <= cnt; i += 8) {
#pragma unroll
        for (int q = 0; q < 8; ++q) {
            half4v a = g4[idx[i + q] * 64 + t];
            acc.x += (float)a[0]; acc.y += (float)a[1];
            acc.z += (float)a[2]; acc.w += (float)a[3];
        }
    }
    for (; i < cnt; ++i) {
        half4v a = g4[idx[i] * 64 + t];
        acc.x += (float)a[0]; acc.y += (float)a[1];
        acc.z += (float)a[2]; acc.w += (float)a[3];
    }
    float sv = rsqrtf((float)deg[v]);
    float4 bb = ((const float4*)b1)[t];
    float4 r;
    r.x = fmaxf(sv * acc.x + bb.x, 0.f);
    r.y = fmaxf(sv * acc.y + bb.y, 0.f);
    r.z = fmaxf(sv * acc.z + bb.z, 0.f);
    r.w = fmaxf(sv * acc.w + bb.w, 0.f);
    ((float4*)h1)[(int64_t)v * 64 + t] = r;
}

__global__ __launch_bounds__(64) void spmm2_kernel(const uint32_t* __restrict__ B,
        const _Float16* __restrict__ g2, const uint32_t* __restrict__ deg,
        const float* __restrict__ b2, float* __restrict__ out) {
    __shared__ uint16_t idx[4096];
    int v = blockIdx.x;
    int t = threadIdx.x;
    uint32_t cnt = build_idx(B, v, t, idx);
    const half2v* gp = (const half2v*)g2;     // row = 64 half2
    float ax = 0.f, ay = 0.f;
    uint32_t i = 0;
    for (; i + 8 <= cnt; i += 8) {
#pragma unroll
        for (int q = 0; q < 8; ++q) {
            half2v a = gp[idx[i + q] * 64 + t];
            ax += (float)a[0]; ay += (float)a[1];
        }
    }
    for (; i < cnt; ++i) {
        half2v a = gp[idx[i] * 64 + t];
        ax += (float)a[0]; ay += (float)a[1];
    }
    float sv = rsqrtf((float)deg[v]);
    float2 bb = ((const float2*)b2)[t];
    float2 r;
    r.x = sv * ax + bb.x;
    r.y = sv * ay + bb.y;
    ((float2*)out)[(int64_t)v * 64 + t] = r;
}

// ---------------------------------------------------------------------------
extern "C" void kernel_launch(void* const* d_in, const int* in_sizes, int n_in,
                              void* d_out, int out_size, void* d_ws, size_t ws_size,
                              hipStream_t stream) {
    const float* x    = (const float*)d_in[0];
    const float* attn = (const float*)d_in[1];
    const float* aggw = (const float*)d_in[2];
    const float* aggb = (const float*)d_in[3];
    const float* W1   = (const float*)d_in[4];
    const float* b1   = (const float*)d_in[5];
    const float* W2   = (const float*)d_in[6];
    const float* b2   = (const float*)d_in[7];
    float* out = (float*)d_out;

    char* ws = (char*)d_ws;
    size_t OFF_AGG   = 0;
    size_t OFF_SLICE = OFF_AGG + (size_t)NNN * 4;                   // 16 MB
    size_t OFF_META  = OFF_SLICE + (size_t)1024 * 4096 * 4;         // 56 KB zeroed
    size_t OFF_M     = OFF_META + 65536;                            // 2 MB rowmask
    size_t OFF_B     = OFF_M + (size_t)N_NODES * 128 * 4;           // 2 MB
    size_t OFF_CV    = OFF_B + (size_t)N_NODES * 128 * 4;           // 64 MB
    size_t OFF_CC    = OFF_CV + (size_t)1024 * CHUNK_V * 4;         // 64 MB
    size_t OFF_G     = OFF_CC + (size_t)1024 * CHUNK_V * 4;         // 2 MB fp16
    size_t OFF_H1    = OFF_G + (size_t)N_NODES * 256 * 2;           // 4 MB
    size_t OFF_G2    = OFF_H1 + (size_t)N_NODES * 256 * 4;          // 1 MB fp16

    float*    agg   = (float*)(ws + OFF_AGG);
    uint32_t* slice = (uint32_t*)(ws + OFF_SLICE);
    uint32_t* meta  = (uint32_t*)(ws + OFF_META);
    uint32_t* Mm    = (uint32_t*)(ws + OFF_M);
    uint32_t* Bm    = (uint32_t*)(ws + OFF_B);
    float*    candV = (float*)(ws + OFF_CV);
    uint32_t* candC = (uint32_t*)(ws + OFF_CC);
    _Float16* g     = (_Float16*)(ws + OFF_G);
    float*    h1    = (float*)(ws + OFF_H1);
    _Float16* g2    = (_Float16*)(ws + OFF_G2);
    uint32_t* deg   = meta + M_DEG;

    agg_kernel<<<1024, 256, 0, stream>>>(attn, aggw, aggb, agg, slice, meta);
    reduce1_kernel<<<256, 256, 0, stream>>>(slice, meta);
    collectM_kernel<<<1024, 256, 0, stream>>>(agg, meta, Mm, candV, candC);
    collect2_kernel<<<1024, 256, 0, stream>>>(candV, meta);
    fixupM_kernel<<<1024, 256, 0, stream>>>(candV, candC, meta, Mm);
    transposeB_kernel<<<1024, 256, 0, stream>>>(Mm, Bm, deg);

    gemm1_kernel<<<512, 256, 0, stream>>>(x, W1, deg, g);
    spmm1_kernel<<<N_NODES, 64, 0, stream>>>(Bm, g, deg, b1, h1);
    gemm2_kernel<<<512, 256, 0, stream>>>(h1, W2, deg, g2);
    spmm2_kernel<<<N_NODES, 64, 0, stream>>>(Bm, g2, deg, b2, out);
}